// Round 19
// baseline (50.101 us; speedup 1.0000x reference)
//
#include <hip/hip_runtime.h>

// BayesTensorRing via paired 32x32x16 MFMA: out[s]=trace(M0'M1'M2'M3').
// Two samples per MFMA pair (block-diag); trace = per-lane pk-dot of X,Z diag
// entries + DPP funnel. Ladder: 72 -> 54 (VMEM-inst halved) -> 51 (VALU cuts)
// -> 45 (occupancy 41%). R18 (32/wave + full unroll) FAILED: unroll -> spills
// -> scratch VMEM corrupts manual vmcnt counting (WAITV(4) no longer isolates
// the 4 operand loads). R19 = 32 samples/wave with R17's ROLLED runtime-bound
// loop (no unroll, no spills): 15625 waves doubles TLP at unchanged pressure.
//
// Layouts (verified R15-R17 pass): A[row=l&31][k=8j+4(l>>5)+i], B[col same],
// C/D: col=l&31, row=(reg&3)+8(reg>>2)+4(l>>5). ws granule order: lane reads
// 16B at slice byte ((l>>5)*16+(l&15))*16, slice select by lane bit4.
// ws: W0@0 | W1@102400 | W2@204800 | W3@307200 (f16, 512B slices). 409600B.

typedef _Float16 f16x8  __attribute__((ext_vector_type(8)));
typedef _Float16 f16x2  __attribute__((ext_vector_type(2)));
typedef float    f32x16 __attribute__((ext_vector_type(16)));
typedef float    f32x2  __attribute__((ext_vector_type(2)));

#define DEV static __device__ __forceinline__

template<int CTRL>
DEV float dppmov(float x)
{
    return __int_as_float(__builtin_amdgcn_update_dpp(
        0, __float_as_int(x), CTRL, 0xF, 0xF, true));
}

DEV f16x8 ldg16s(const _Float16* sbase, int voff)
{
    f16x8 d;
    asm volatile("global_load_dwordx4 %0, %1, %2"
                 : "=&v"(d) : "v"(voff), "s"(sbase) : "memory");
    return d;
}

DEV f32x2 pkfma(f32x2 a, f32x2 b, f32x2 c)
{
    f32x2 d;
    asm("v_pk_fma_f32 %0, %1, %2, %3" : "=v"(d) : "v"(a), "v"(b), "v"(c));
    return d;
}

#define WAITV(N) asm volatile("s_waitcnt vmcnt(" #N ")" ::: "memory")
#define RL(v, l) __builtin_amdgcn_readlane((v), (l))

union Acc16 { f32x16 v; f32x2 p[8]; };

__global__ __launch_bounds__(256, 6)
void mfma_chain(const int* __restrict__ idx, const char* __restrict__ wsb,
                float* __restrict__ out, int n)
{
    const _Float16* W0 = (const _Float16*)(wsb);
    const _Float16* W1 = (const _Float16*)(wsb + 102400);
    const _Float16* W2 = (const _Float16*)(wsb + 204800);
    const _Float16* W3 = (const _Float16*)(wsb + 307200);

    const int lane = threadIdx.x & 63;
    const int wv   = (blockIdx.x << 2) | (threadIdx.x >> 6);
    const int s0   = __builtin_amdgcn_readfirstlane(wv << 5);   // 32 samples/wave
    if (s0 >= n) return;
    const int cnt  = (n - s0 < 32) ? (n - s0) : 32;             // 32 here (n%32==0)

    const int voff = ((lane >> 5) << 8) + ((lane & 15) << 4);   // in-slice byte off
    const int hiI  = (lane >> 4) & 1;       // serves sample t+1
    const bool clow = (lane & 31) < 16;     // col<16 -> sample t diag block

    // lanes 0..31 hold idx rows for samples s0..s0+31 (32..63 duplicate, unused)
    const int li = lane & 31;
    const int sl = s0 + li < n ? s0 + li : n - 1;
    const int4 vidx = *(const int4*)(idx + 4l * sl);
    const int vo0 = (vidx.x << 9), vo1 = (vidx.y << 9);
    const int vo2 = (vidx.z << 9), vo3 = (vidx.w << 9);

    float res = 0.f;
    const f32x16 zacc = {};

    #define ISSUE(S, t) {                                                    \
        const int tb   = (t) <= 30 ? (t) : 30;                               \
        const int tsel = tb | hiI;                                           \
        S##a0 = ldg16s(W0, __shfl(vo0, tsel) + voff);                        \
        S##b1 = ldg16s(W1, __shfl(vo1, tsel) + voff);                        \
        S##b2 = ldg16s(W2, __shfl(vo2, tsel) + voff);                        \
        S##a3 = ldg16s(W3, __shfl(vo3, tsel) + voff);                        \
    }

    #define COMP(S, t) {                                                     \
        WAITV(4);                                                            \
        __builtin_amdgcn_sched_barrier(0);                                   \
        Acc16 X, Z;                                                          \
        X.v = __builtin_amdgcn_mfma_f32_32x32x16_f16(S##a0, S##b1, zacc, 0, 0, 0); \
        Z.v = __builtin_amdgcn_mfma_f32_32x32x16_f16(S##a3, S##b2, zacc, 0, 0, 0); \
        f32x2 zero2 = {0.f, 0.f};                                            \
        f32x2 dlo = pkfma(X.p[0], Z.p[0], zero2);                            \
        dlo = pkfma(X.p[1], Z.p[1], dlo);                                    \
        dlo = pkfma(X.p[2], Z.p[2], dlo);                                    \
        dlo = pkfma(X.p[3], Z.p[3], dlo);                                    \
        f32x2 dhi = pkfma(X.p[4], Z.p[4], zero2);                            \
        dhi = pkfma(X.p[5], Z.p[5], dhi);                                    \
        dhi = pkfma(X.p[6], Z.p[6], dhi);                                    \
        dhi = pkfma(X.p[7], Z.p[7], dhi);                                    \
        const float sA = clow ? dlo[0] : dhi[0];                             \
        const float sB = clow ? dlo[1] : dhi[1];                             \
        float p = sA + sB;                                                   \
        p += dppmov<0x111>(p);                                               \
        p += dppmov<0x112>(p);                                               \
        p += dppmov<0x114>(p);                                               \
        p += dppmov<0x118>(p);                                               \
        p += __shfl_xor(p, 32);                                              \
        const int pa = RL(__float_as_int(p), 15);                            \
        const int pb = RL(__float_as_int(p), 31);                            \
        res = (lane == (t))     ? __int_as_float(pa) : res;                  \
        res = (lane == (t) + 1) ? __int_as_float(pb) : res;                  \
    }

    f16x8 Aa0, Ab1, Ab2, Aa3;
    f16x8 Ba0, Bb1, Bb2, Ba3;

    ISSUE(A, 0); ISSUE(B, 2);

    const int cntR = (cnt + 3) & ~3;     // 32 (runtime -> loop stays rolled)
    for (int t = 0; t + 4 <= cntR; t += 4) {
        COMP(A, t);     ISSUE(A, t + 4);
        COMP(B, t + 2); ISSUE(B, t + 6);
    }

    if (lane < cnt) out[s0 + lane] = res;   // coalesced 128B store per wave

    #undef ISSUE
    #undef COMP
}

// Prescale into granule order (same as R15-R17, verified). pr: g=pr>>2, w=pr&3;
// h=g>>4, q=g&15; k0=8*(w>>1)+4*h+2*(w&1); dst slice pos g*8+2w.
__global__ __launch_bounds__(256)
void prescale_kernel(const float* __restrict__ cr0, const float* __restrict__ lm0,
                     const float* __restrict__ cr1, const float* __restrict__ lm1,
                     const float* __restrict__ cr2, const float* __restrict__ lm2,
                     const float* __restrict__ cr3, const float* __restrict__ lm3,
                     char* __restrict__ wsb)
{
    _Float16* W0 = (_Float16*)(wsb);
    _Float16* W1 = (_Float16*)(wsb + 102400);
    _Float16* W2 = (_Float16*)(wsb + 204800);
    _Float16* W3 = (_Float16*)(wsb + 307200);

    const int bx  = blockIdx.x;
    const int d   = bx / 100;
    const int gid = (bx % 100) * 256 + threadIdx.x;
    const int i   = gid >> 7;
    const int pr  = gid & 127;

    const int g  = pr >> 2, w = pr & 3;
    const int h  = g >> 4,  q = g & 15;
    const int k0 = 8 * (w >> 1) + 4 * h + 2 * (w & 1);
    const int dstpos = i * 256 + g * 8 + 2 * w;

    if (d == 0 || d == 2) {
        const float* cp = (d == 0) ? cr0 : cr2;
        const float* lp = (d == 0) ? lm0 : lm2;
        _Float16*    Wt = (d == 0) ? W0 : W2;
        const float2 v = *(const float2*)(cp + i * 256 + q * 16 + k0);
        f16x2 o; o[0] = (_Float16)(v.x * lp[k0]); o[1] = (_Float16)(v.y * lp[k0 + 1]);
        *(f16x2*)(Wt + dstpos) = o;
    } else {
        const float* cp = (d == 1) ? cr1 : cr3;
        const float* lp = (d == 1) ? lm1 : lm3;
        _Float16*    Wt = (d == 1) ? W1 : W3;
        const float a = cp[i * 256 + k0 * 16 + q]       * lp[q];
        const float b = cp[i * 256 + (k0 + 1) * 16 + q] * lp[q];
        f16x2 o; o[0] = (_Float16)a; o[1] = (_Float16)b;
        *(f16x2*)(Wt + dstpos) = o;
    }
}

// ---------------- fallback (no workspace): R5 DPP vector kernel ----------------
template<int CTRL>
DEV float dppf(float x)
{
    return __int_as_float(__builtin_amdgcn_update_dpp(
        0, __float_as_int(x), CTRL, 0xF, 0xF, true));
}

DEV void mm16g_lam(const float (&a)[4][16], float (&b)[4][16],
                   const float* __restrict__ m, const float* __restrict__ lam)
{
    const float4* m4 = reinterpret_cast<const float4*>(m);
    float4 lv[4];
#pragma unroll
    for (int q = 0; q < 4; ++q) lv[q] = reinterpret_cast<const float4*>(lam)[q];
#pragma unroll
    for (int nn = 0; nn < 16; ++nn) {
        float mrow[16];
#pragma unroll
        for (int q = 0; q < 4; ++q) {
            float4 v = m4[4 * nn + q];
            v.x *= lv[q].x; v.y *= lv[q].y; v.z *= lv[q].z; v.w *= lv[q].w;
            mrow[4*q+0] = v.x; mrow[4*q+1] = v.y;
            mrow[4*q+2] = v.z; mrow[4*q+3] = v.w;
        }
#pragma unroll
        for (int r = 0; r < 4; ++r) {
            const float av = a[r][nn];
            if (nn == 0) {
#pragma unroll
                for (int k = 0; k < 16; ++k) b[r][k] = av * mrow[k];
            } else {
#pragma unroll
                for (int k = 0; k < 16; ++k) b[r][k] = fmaf(av, mrow[k], b[r][k]);
            }
        }
    }
}

__global__ __launch_bounds__(256)
void chain_kernel_fb(const int* __restrict__ idx,
                     const float* __restrict__ c0, const float* __restrict__ l0,
                     const float* __restrict__ c1, const float* __restrict__ l1,
                     const float* __restrict__ c2, const float* __restrict__ l2,
                     const float* __restrict__ c3, const float* __restrict__ l3,
                     float* __restrict__ out, int n)
{
    const int tid  = threadIdx.x;
    const int slot = tid >> 2;
    const int j    = tid & 3;
    const int s    = blockIdx.x * 64 + slot;
    const int sc   = s < n ? s : n - 1;

    const int4 ix = *reinterpret_cast<const int4*>(idx + 4l * sc);

    float a[4][16], b[4][16];
    {
        const float4* src = reinterpret_cast<const float4*>(c0 + 256l * ix.x) + 16 * j;
#pragma unroll
        for (int t = 0; t < 16; ++t) {
            float4 v = src[t];
            const float4 L = reinterpret_cast<const float4*>(l0)[t & 3];
            const int r = t >> 2, c = (t & 3) * 4;
            a[r][c+0] = v.x * L.x; a[r][c+1] = v.y * L.y;
            a[r][c+2] = v.z * L.z; a[r][c+3] = v.w * L.w;
        }
    }

    mm16g_lam(a, b, c1 + 256l * ix.y, l1);
    mm16g_lam(b, a, c2 + 256l * ix.z, l2);

    float4 part = make_float4(0.f, 0.f, 0.f, 0.f);
    const float* base3 = c3 + 256l * ix.w + 4 * j;
#pragma unroll
    for (int nn = 0; nn < 16; ++nn) {
        const float4 v = *reinterpret_cast<const float4*>(base3 + 16 * nn);
        part.x = fmaf(a[0][nn], v.x, part.x);
        part.y = fmaf(a[1][nn], v.y, part.y);
        part.z = fmaf(a[2][nn], v.z, part.z);
        part.w = fmaf(a[3][nn], v.w, part.w);
    }
    const float4 L3 = reinterpret_cast<const float4*>(l3)[j];
    float p = part.x * L3.x + part.y * L3.y + part.z * L3.z + part.w * L3.w;

    p += __shfl_xor(p, 1);
    p += __shfl_xor(p, 2);

    if (s < n && j == 0) out[s] = p;
}

extern "C" void kernel_launch(void* const* d_in, const int* in_sizes, int n_in,
                              void* d_out, int out_size, void* d_ws, size_t ws_size,
                              hipStream_t stream)
{
    const int*   idx = (const int*)  d_in[0];
    const float* c0  = (const float*)d_in[1];
    const float* l0  = (const float*)d_in[2];
    const float* c1  = (const float*)d_in[3];
    const float* l1  = (const float*)d_in[4];
    const float* c2  = (const float*)d_in[5];
    const float* l2  = (const float*)d_in[6];
    const float* c3  = (const float*)d_in[7];
    const float* l3  = (const float*)d_in[8];
    float* out = (float*)d_out;

    const int n = out_size;                       // 500000

    if (ws_size >= 409600) {
        char* wsb = (char*)d_ws;
        hipLaunchKernelGGL(prescale_kernel, dim3(400), dim3(256), 0, stream,
                           c0, l0, c1, l1, c2, l2, c3, l3, wsb);
        const int waves  = (n + 31) / 32;         // 15625
        const int blocks = (waves + 3) / 4;       // 3907
        hipLaunchKernelGGL(mfma_chain, dim3(blocks), dim3(256), 0, stream,
                           idx, wsb, out, n);
    } else {
        const int grid = (n + 63) / 64;
        hipLaunchKernelGGL(chain_kernel_fb, dim3(grid), dim3(256), 0, stream,
                           idx, c0, l0, c1, l1, c2, l2, c3, l3, out, n);
    }
}

// Round 20
// 48.002 us; speedup vs baseline: 1.0437x; 1.0437x over previous
//
#include <hip/hip_runtime.h>

// BayesTensorRing via paired 32x32x16 MFMA: out[s]=trace(M0'M1'M2'M3').
// Two samples per MFMA pair (block-diag); trace = per-lane pk-dot of X,Z diag
// entries + DPP funnel. Ladder: 72 -> 54 (VMEM-inst halved) -> 51 (VALU cuts)
// -> 45-46 chain (occupancy 41%, R17). R18 (unroll) failed: spills corrupt
// manual vmcnt. R19 (32/wave) flat: occupancy wasn't binding. R20 (this):
// back to 64/wave 2-state, + address-prep pipelining (SHFL one pair ahead of
// LOAD - takes ~100cyc ds_bpermute latency off the load-issue path), + peeled
// epilogue with exact waits (zero wasted clamped loads), + launch_bounds(256,4)
// (128 VGPR cap: spill-proof).
//
// Layouts (verified R15-R19 pass): A[row=l&31][k=8j+4(l>>5)+i], B[col same],
// C/D: col=l&31, row=(reg&3)+8(reg>>2)+4(l>>5). ws granule order: lane reads
// 16B at slice byte ((l>>5)*16+(l&15))*16, slice select by lane bit4.
// ws: W0@0 | W1@102400 | W2@204800 | W3@307200 (f16, 512B slices). 409600B.

typedef _Float16 f16x8  __attribute__((ext_vector_type(8)));
typedef _Float16 f16x2  __attribute__((ext_vector_type(2)));
typedef float    f32x16 __attribute__((ext_vector_type(16)));
typedef float    f32x2  __attribute__((ext_vector_type(2)));

#define DEV static __device__ __forceinline__

template<int CTRL>
DEV float dppmov(float x)
{
    return __int_as_float(__builtin_amdgcn_update_dpp(
        0, __float_as_int(x), CTRL, 0xF, 0xF, true));
}

DEV f16x8 ldg16s(const _Float16* sbase, int voff)
{
    f16x8 d;
    asm volatile("global_load_dwordx4 %0, %1, %2"
                 : "=&v"(d) : "v"(voff), "s"(sbase) : "memory");
    return d;
}

DEV f32x2 pkfma(f32x2 a, f32x2 b, f32x2 c)
{
    f32x2 d;
    asm("v_pk_fma_f32 %0, %1, %2, %3" : "=v"(d) : "v"(a), "v"(b), "v"(c));
    return d;
}

#define WAITVN_(N) asm volatile("s_waitcnt vmcnt(" #N ")" ::: "memory")
#define WAITVN(N)  WAITVN_(N)
#define RL(v, l)   __builtin_amdgcn_readlane((v), (l))

union Acc16 { f32x16 v; f32x2 p[8]; };

__global__ __launch_bounds__(256, 4)
void mfma_chain(const int* __restrict__ idx, const char* __restrict__ wsb,
                float* __restrict__ out, int n)
{
    const _Float16* W0 = (const _Float16*)(wsb);
    const _Float16* W1 = (const _Float16*)(wsb + 102400);
    const _Float16* W2 = (const _Float16*)(wsb + 204800);
    const _Float16* W3 = (const _Float16*)(wsb + 307200);

    const int lane = threadIdx.x & 63;
    const int wv   = (blockIdx.x << 2) | (threadIdx.x >> 6);
    const int s0   = __builtin_amdgcn_readfirstlane(wv << 6);   // 64 samples/wave
    if (s0 >= n) return;
    const int cnt  = (n - s0 < 64) ? (n - s0) : 64;             // 64 or 32

    const int voff = ((lane >> 5) << 8) + ((lane & 15) << 4);   // in-slice byte off
    const int hiI  = (lane >> 4) & 1;       // serves sample t+1
    const bool clow = (lane & 31) < 16;     // col<16 -> sample t diag block

    const int lc = lane < cnt ? lane : cnt - 1;
    const int4 vidx = *(const int4*)(idx + 4l * (s0 + lc));
    const int vo0 = (vidx.x << 9), vo1 = (vidx.y << 9);
    const int vo2 = (vidx.z << 9), vo3 = (vidx.w << 9);

    float res = 0.f;
    const f32x16 zacc = {};

    // address prep (ds_bpermute latency hidden: done one pair ahead of LOAD)
    #define SHFL(S, t) {                                                     \
        const int tb   = (t) <= 62 ? (t) : 62;                               \
        const int tsel = tb | hiI;                                           \
        S##o0 = __shfl(vo0, tsel) + voff;                                    \
        S##o1 = __shfl(vo1, tsel) + voff;                                    \
        S##o2 = __shfl(vo2, tsel) + voff;                                    \
        S##o3 = __shfl(vo3, tsel) + voff;                                    \
    }
    // issue the 4 gathers from prepped addresses
    #define LOAD(S) {                                                        \
        S##a0 = ldg16s(W0, S##o0);                                           \
        S##b1 = ldg16s(W1, S##o1);                                           \
        S##b2 = ldg16s(W2, S##o2);                                           \
        S##a3 = ldg16s(W3, S##o3);                                           \
    }

    #define COMP(S, t, N) {                                                  \
        WAITVN(N);                                                           \
        __builtin_amdgcn_sched_barrier(0);                                   \
        Acc16 X, Z;                                                          \
        X.v = __builtin_amdgcn_mfma_f32_32x32x16_f16(S##a0, S##b1, zacc, 0, 0, 0); \
        Z.v = __builtin_amdgcn_mfma_f32_32x32x16_f16(S##a3, S##b2, zacc, 0, 0, 0); \
        f32x2 zero2 = {0.f, 0.f};                                            \
        f32x2 dlo = pkfma(X.p[0], Z.p[0], zero2);                            \
        dlo = pkfma(X.p[1], Z.p[1], dlo);                                    \
        dlo = pkfma(X.p[2], Z.p[2], dlo);                                    \
        dlo = pkfma(X.p[3], Z.p[3], dlo);                                    \
        f32x2 dhi = pkfma(X.p[4], Z.p[4], zero2);                            \
        dhi = pkfma(X.p[5], Z.p[5], dhi);                                    \
        dhi = pkfma(X.p[6], Z.p[6], dhi);                                    \
        dhi = pkfma(X.p[7], Z.p[7], dhi);                                    \
        const float sA = clow ? dlo[0] : dhi[0];                             \
        const float sB = clow ? dlo[1] : dhi[1];                             \
        float p = sA + sB;                                                   \
        p += dppmov<0x111>(p);                                               \
        p += dppmov<0x112>(p);                                               \
        p += dppmov<0x114>(p);                                               \
        p += dppmov<0x118>(p);                                               \
        p += __shfl_xor(p, 32);                                              \
        const int pa = RL(__float_as_int(p), 15);                            \
        const int pb = RL(__float_as_int(p), 31);                            \
        res = (lane == (t))     ? __int_as_float(pa) : res;                  \
        res = (lane == (t) + 1) ? __int_as_float(pb) : res;                  \
    }

    f16x8 Aa0, Ab1, Ab2, Aa3;
    f16x8 Ba0, Bb1, Bb2, Ba3;
    int Ao0, Ao1, Ao2, Ao3;
    int Bo0, Bo1, Bo2, Bo3;

    // prologue: loads for pairs @0 and @2 in flight; addrs for @4 and @6 prepped
    SHFL(A, 0); LOAD(A);
    SHFL(B, 2); LOAD(B);
    SHFL(A, 4);
    SHFL(B, 6);

    // main loop: consume t, t+2; issue t+4, t+6 from prepped addrs; prep t+8, t+10
    int t = 0;
    for (; t + 8 <= cnt; t += 4) {
        COMP(A, t, 4);     LOAD(A); SHFL(A, t + 8);
        COMP(B, t + 2, 4); LOAD(B); SHFL(B, t + 10);
    }
    // epilogue: exactly two pairs left in flight (no wasted issues)
    COMP(A, t, 4);
    COMP(B, t + 2, 0);

    if (lane < cnt) out[s0 + lane] = res;   // one coalesced store per wave

    #undef SHFL
    #undef LOAD
    #undef COMP
}

// Prescale into granule order (same as R15-R19, verified). pr: g=pr>>2, w=pr&3;
// h=g>>4, q=g&15; k0=8*(w>>1)+4*h+2*(w&1); dst slice pos g*8+2w.
__global__ __launch_bounds__(256)
void prescale_kernel(const float* __restrict__ cr0, const float* __restrict__ lm0,
                     const float* __restrict__ cr1, const float* __restrict__ lm1,
                     const float* __restrict__ cr2, const float* __restrict__ lm2,
                     const float* __restrict__ cr3, const float* __restrict__ lm3,
                     char* __restrict__ wsb)
{
    _Float16* W0 = (_Float16*)(wsb);
    _Float16* W1 = (_Float16*)(wsb + 102400);
    _Float16* W2 = (_Float16*)(wsb + 204800);
    _Float16* W3 = (_Float16*)(wsb + 307200);

    const int bx  = blockIdx.x;
    const int d   = bx / 100;
    const int gid = (bx % 100) * 256 + threadIdx.x;
    const int i   = gid >> 7;
    const int pr  = gid & 127;

    const int g  = pr >> 2, w = pr & 3;
    const int h  = g >> 4,  q = g & 15;
    const int k0 = 8 * (w >> 1) + 4 * h + 2 * (w & 1);
    const int dstpos = i * 256 + g * 8 + 2 * w;

    if (d == 0 || d == 2) {
        const float* cp = (d == 0) ? cr0 : cr2;
        const float* lp = (d == 0) ? lm0 : lm2;
        _Float16*    Wt = (d == 0) ? W0 : W2;
        const float2 v = *(const float2*)(cp + i * 256 + q * 16 + k0);
        f16x2 o; o[0] = (_Float16)(v.x * lp[k0]); o[1] = (_Float16)(v.y * lp[k0 + 1]);
        *(f16x2*)(Wt + dstpos) = o;
    } else {
        const float* cp = (d == 1) ? cr1 : cr3;
        const float* lp = (d == 1) ? lm1 : lm3;
        _Float16*    Wt = (d == 1) ? W1 : W3;
        const float a = cp[i * 256 + k0 * 16 + q]       * lp[q];
        const float b = cp[i * 256 + (k0 + 1) * 16 + q] * lp[q];
        f16x2 o; o[0] = (_Float16)a; o[1] = (_Float16)b;
        *(f16x2*)(Wt + dstpos) = o;
    }
}

// ---------------- fallback (no workspace): R5 DPP vector kernel ----------------
template<int CTRL>
DEV float dppf(float x)
{
    return __int_as_float(__builtin_amdgcn_update_dpp(
        0, __float_as_int(x), CTRL, 0xF, 0xF, true));
}

DEV void mm16g_lam(const float (&a)[4][16], float (&b)[4][16],
                   const float* __restrict__ m, const float* __restrict__ lam)
{
    const float4* m4 = reinterpret_cast<const float4*>(m);
    float4 lv[4];
#pragma unroll
    for (int q = 0; q < 4; ++q) lv[q] = reinterpret_cast<const float4*>(lam)[q];
#pragma unroll
    for (int nn = 0; nn < 16; ++nn) {
        float mrow[16];
#pragma unroll
        for (int q = 0; q < 4; ++q) {
            float4 v = m4[4 * nn + q];
            v.x *= lv[q].x; v.y *= lv[q].y; v.z *= lv[q].z; v.w *= lv[q].w;
            mrow[4*q+0] = v.x; mrow[4*q+1] = v.y;
            mrow[4*q+2] = v.z; mrow[4*q+3] = v.w;
        }
#pragma unroll
        for (int r = 0; r < 4; ++r) {
            const float av = a[r][nn];
            if (nn == 0) {
#pragma unroll
                for (int k = 0; k < 16; ++k) b[r][k] = av * mrow[k];
            } else {
#pragma unroll
                for (int k = 0; k < 16; ++k) b[r][k] = fmaf(av, mrow[k], b[r][k]);
            }
        }
    }
}

__global__ __launch_bounds__(256)
void chain_kernel_fb(const int* __restrict__ idx,
                     const float* __restrict__ c0, const float* __restrict__ l0,
                     const float* __restrict__ c1, const float* __restrict__ l1,
                     const float* __restrict__ c2, const float* __restrict__ l2,
                     const float* __restrict__ c3, const float* __restrict__ l3,
                     float* __restrict__ out, int n)
{
    const int tid  = threadIdx.x;
    const int slot = tid >> 2;
    const int j    = tid & 3;
    const int s    = blockIdx.x * 64 + slot;
    const int sc   = s < n ? s : n - 1;

    const int4 ix = *reinterpret_cast<const int4*>(idx + 4l * sc);

    float a[4][16], b[4][16];
    {
        const float4* src = reinterpret_cast<const float4*>(c0 + 256l * ix.x) + 16 * j;
#pragma unroll
        for (int t = 0; t < 16; ++t) {
            float4 v = src[t];
            const float4 L = reinterpret_cast<const float4*>(l0)[t & 3];
            const int r = t >> 2, c = (t & 3) * 4;
            a[r][c+0] = v.x * L.x; a[r][c+1] = v.y * L.y;
            a[r][c+2] = v.z * L.z; a[r][c+3] = v.w * L.w;
        }
    }

    mm16g_lam(a, b, c1 + 256l * ix.y, l1);
    mm16g_lam(b, a, c2 + 256l * ix.z, l2);

    float4 part = make_float4(0.f, 0.f, 0.f, 0.f);
    const float* base3 = c3 + 256l * ix.w + 4 * j;
#pragma unroll
    for (int nn = 0; nn < 16; ++nn) {
        const float4 v = *reinterpret_cast<const float4*>(base3 + 16 * nn);
        part.x = fmaf(a[0][nn], v.x, part.x);
        part.y = fmaf(a[1][nn], v.y, part.y);
        part.z = fmaf(a[2][nn], v.z, part.z);
        part.w = fmaf(a[3][nn], v.w, part.w);
    }
    const float4 L3 = reinterpret_cast<const float4*>(l3)[j];
    float p = part.x * L3.x + part.y * L3.y + part.z * L3.z + part.w * L3.w;

    p += __shfl_xor(p, 1);
    p += __shfl_xor(p, 2);

    if (s < n && j == 0) out[s] = p;
}

extern "C" void kernel_launch(void* const* d_in, const int* in_sizes, int n_in,
                              void* d_out, int out_size, void* d_ws, size_t ws_size,
                              hipStream_t stream)
{
    const int*   idx = (const int*)  d_in[0];
    const float* c0  = (const float*)d_in[1];
    const float* l0  = (const float*)d_in[2];
    const float* c1  = (const float*)d_in[3];
    const float* l1  = (const float*)d_in[4];
    const float* c2  = (const float*)d_in[5];
    const float* l2  = (const float*)d_in[6];
    const float* c3  = (const float*)d_in[7];
    const float* l3  = (const float*)d_in[8];
    float* out = (float*)d_out;

    const int n = out_size;                       // 500000

    if (ws_size >= 409600) {
        char* wsb = (char*)d_ws;
        hipLaunchKernelGGL(prescale_kernel, dim3(400), dim3(256), 0, stream,
                           c0, l0, c1, l1, c2, l2, c3, l3, wsb);
        const int waves  = (n + 63) / 64;         // 7813
        const int blocks = (waves + 3) / 4;       // 1954
        hipLaunchKernelGGL(mfma_chain, dim3(blocks), dim3(256), 0, stream,
                           idx, wsb, out, n);
    } else {
        const int grid = (n + 63) / 64;
        hipLaunchKernelGGL(chain_kernel_fb, dim3(grid), dim3(256), 0, stream,
                           idx, c0, l0, c1, l1, c2, l2, c3, l3, out, n);
    }
}